// Round 6
// baseline (11630.613 us; speedup 1.0000x reference)
//
#include <hip/hip_runtime.h>

// 2-layer LSTM, B=64, S=2048, F=40, EMB=128, HID=256.
// Persistent design, R8: MERGED-LAYER blocks, R2-exact memory footprint.
//   R7 (PIPE=8, 2MB workspace) killed the container -> suspected ws_size OOB.
//   R8 keeps PIPE=4 and the EXACT R2 workspace/LDS layout (1MB ws, 46848B LDS).
//   Topology: 32 active blocks (64 launched, g=bx&7<4, p=bx>>3). Each block owns
//   32 h-cols for BOTH layers. Per step t in [0..Sz]:
//     poll{ srcA0=h0(t-1)->HA, srcA1=h1(t-2)->HB } (R2-exact full reload + vote)
//     -> compute+publish L0(t)   (recurrence from HA, input from IN/wcomb)
//     -> compute+publish L1(t-1) (recurrence from HB, input stream = HA again!)
//   DELTA=1 makes L1's input h0(t-1) the SAME slab staged for L0's recurrence:
//   only 2 staged sources, no third load. L1 compute fills the old spin window,
//   so peers' next-step polls hit fresh tags with fewer retries.
//   Protocol building blocks R2-verbatim: u64 {tag32, bf16hi|bf16lo} RELAXED
//   agent atomics, full tagged reload every poll iteration, block vote, cflg
//   guard (c >= t-2; subsumed by srcA0 tag-wait except at the t=Sz tail).
//   Overwrite safety: L0(t) kills L0(t-4), last read at step t-3; L1(t-1) kills
//   L1(t-5), last read at step t-3; both covered by guard. Zeroed slots serve
//   h(-1)=0 via embedded tag 0.
//   Numerics identical to R2: weights bf16, A hi/lo bf16 split, fp32 c/h/gates.

#define Sz    2048
#define PIPE  4
#define NG    4
#define NJ    8

typedef __attribute__((ext_vector_type(8))) short short8;
typedef __attribute__((ext_vector_type(4))) float f32x4;

// workspace layout (byte-identical to R2)
#define PUB0_U64 0            // [g][slot(4)][p(8)][512] u64
#define PUB1_U64 65536
#define CFLG_U32 262144       // 32 u32: per-block step-completion counters [g*8+p]
#define WS_U32   262176

// LDS byte offsets (byte-identical to R2)
#define HA_HI 0               // h0(t-1): L0 recurrence input AND L1 input stream
#define HA_LO 8448
#define HB_HI 16896           // h1(t-2): L1 recurrence input
#define HB_LO 25344
#define IN_HI 33792           // xin(t) bf16 hi/lo (pad 40->64)
#define IN_LO 36096
#define GBUF  38400
#define SMEM_BYTES 46848
#define WCOMB_OFF 16896       // aliases HB region, used only pre-loop

__device__ __forceinline__ unsigned short bf16_rne(float f) {
  unsigned u = __float_as_uint(f);
  u += 0x7FFFu + ((u >> 16) & 1u);
  return (unsigned short)(u >> 16);
}
__device__ __forceinline__ float sigm(float x) { return 1.f / (1.f + __expf(-x)); }
__device__ __forceinline__ float tanh_f(float x) { return 1.f - 2.f / (__expf(2.f * x) + 1.f); }

// R2-verbatim: load one slot's 8 slabs (4096 u64) across 256 threads, check
// embedded tags, stage bf16 hi/lo planes into LDS. Per-thread tag-ok predicate.
__device__ __forceinline__ bool load_stage(const unsigned long long* __restrict__ src,
                                           unsigned tagExp, char* hi, char* lo, int tid) {
  unsigned long long v[16];
#pragma unroll
  for (int kt = 0; kt < 8; ++kt) {
    v[kt * 2]     = __hip_atomic_load(src + kt * 512 + tid,       __ATOMIC_RELAXED, __HIP_MEMORY_SCOPE_AGENT);
    v[kt * 2 + 1] = __hip_atomic_load(src + kt * 512 + 256 + tid, __ATOMIC_RELAXED, __HIP_MEMORY_SCOPE_AGENT);
  }
  bool ok = true;
#pragma unroll
  for (int kt = 0; kt < 8; ++kt) {
#pragma unroll
    for (int hh = 0; hh < 2; ++hh) {
      unsigned long long x = v[kt * 2 + hh];
      ok &= ((unsigned)(x >> 32) == tagExp);
      unsigned pk = (unsigned)x;
      int e = tid + hh * 256;
      int m = e >> 5, col = kt * 32 + (e & 31);
      *(short*)(hi + m * 528 + col * 2) = (short)(pk >> 16);
      *(short*)(lo + m * 528 + col * 2) = (short)(pk & 0xffffu);
    }
  }
  return ok;
}

__global__ void zero_kernel(unsigned* __restrict__ ws, float* __restrict__ out) {
  int i = blockIdx.x * 256 + threadIdx.x;
  if (i < WS_U32) ws[i] = 0u;
  if (i < 64 * Sz) out[i] = 0.f;
}

__global__ __launch_bounds__(256, 1) void lstm_persist(
    const float* __restrict__ xin, const float* __restrict__ W_in,
    const float* __restrict__ b_in, const float* __restrict__ W_ih0,
    const float* __restrict__ W_hh0, const float* __restrict__ b_ih0,
    const float* __restrict__ b_hh0, const float* __restrict__ W_ih1,
    const float* __restrict__ W_hh1, const float* __restrict__ b_ih1,
    const float* __restrict__ b_hh1, const float* __restrict__ W_out,
    const float* __restrict__ b_out, float* __restrict__ out,
    unsigned* __restrict__ ws) {
  const int bx = blockIdx.x;
  const int g = bx & 7;          // group -> XCD class (locality heuristic only)
  if (g >= NG) return;
  const int p = bx >> 3;         // 0..7 h-col slice (both layers)
  const int tid = (int)threadIdx.x;
  const int w = tid >> 6;        // wave = gate (i,f,g,o)
  const int lane = tid & 63;
  const int q = lane >> 4;
  const int n16 = lane & 15;

  __shared__ __align__(16) char smem[SMEM_BYTES];

  const int row0 = w * 256 + p * 32 + n16;   // absolute gate rows (u=0,1)
  const int row1 = row0 + 16;

  short8 wf_rec0[8][2];  // W_hh0 frags [ktile][u]
  short8 wf_rec1[8][2];  // W_hh1 frags
  short8 wf_in2[8][2];   // W_ih1 frags
  short8 wf_cmb[2][2];   // W_comb = W_ih0@W_in frags (K padded 40->64)
  float b0L0, b1L0, b0L1, b1L1;

  // ---------------- startup: persistent weight fragments (all 4 sets) --------
#pragma unroll
  for (int kt = 0; kt < 8; ++kt) {
#pragma unroll
    for (int u = 0; u < 2; ++u) {
      const int row = u ? row1 : row0;
      const float* s0 = W_hh0 + (size_t)row * 256 + kt * 32 + q * 8;
      const float* s1 = W_hh1 + (size_t)row * 256 + kt * 32 + q * 8;
      const float* s2 = W_ih1 + (size_t)row * 256 + kt * 32 + q * 8;
      union { short8 v; unsigned short s[8]; } f0, f1, f2;
#pragma unroll
      for (int j = 0; j < 8; ++j) {
        f0.s[j] = bf16_rne(s0[j]);
        f1.s[j] = bf16_rne(s1[j]);
        f2.s[j] = bf16_rne(s2[j]);
      }
      wf_rec0[kt][u] = f0.v;
      wf_rec1[kt][u] = f1.v;
      wf_in2[kt][u]  = f2.v;
    }
  }
  b0L1 = b_ih1[row0] + b_hh1[row0];
  b1L1 = b_ih1[row1] + b_hh1[row1];

  {  // W_comb = W_ih0 @ W_in for this block's 128 gate rows, staged via LDS
    float* wcomb = (float*)(smem + WCOMB_OFF);
    for (int i = tid; i < 128 * 40; i += 256) {
      int rl = i / 40, f = i - rl * 40;
      int gate = rl >> 5, rr = rl & 31;
      int arow = gate * 256 + p * 32 + rr;
      const float* wi = W_ih0 + (size_t)arow * 128;
      float s = 0.f;
      for (int e = 0; e < 128; ++e) s += wi[e] * W_in[e * 40 + f];
      wcomb[rl * 40 + f] = s;
    }
    __syncthreads();
#pragma unroll
    for (int kt = 0; kt < 2; ++kt) {
#pragma unroll
      for (int u = 0; u < 2; ++u) {
        int rl = w * 32 + u * 16 + n16;
        union { short8 v; unsigned short s[8]; } fr;
#pragma unroll
        for (int j = 0; j < 8; ++j) {
          int k = kt * 32 + q * 8 + j;
          fr.s[j] = (k < 40) ? bf16_rne(wcomb[rl * 40 + k]) : (unsigned short)0;
        }
        wf_cmb[kt][u] = fr.v;
      }
    }
    {
      const float* wi0 = W_ih0 + (size_t)row0 * 128;
      const float* wi1 = W_ih0 + (size_t)row1 * 128;
      float s0 = 0.f, s1 = 0.f;
      for (int e = 0; e < 128; ++e) { s0 += wi0[e] * b_in[e]; s1 += wi1[e] * b_in[e]; }
      b0L0 = s0 + b_ih0[row0] + b_hh0[row0];
      b1L0 = s1 + b_ih0[row1] + b_hh0[row1];
    }
    __syncthreads();  // done with wcomb alias (HB region)
    // zero input planes once (cols 40..63 stay zero forever; covers HI+LO)
    for (int i = tid; i < 2304; i += 256) *((short*)(smem + IN_HI) + i) = 0;
    __syncthreads();
  }

  float cL0_0 = 0.f, cL0_1 = 0.f;   // layer-0 cell state (e=tid, e=tid+256)
  float cL1_0 = 0.f, cL1_1 = 0.f;   // layer-1 cell state
  const float wo = W_out[p * 32 + (tid & 31)];
  const float bo = b_out[0];

  unsigned long long* const pub0 = (unsigned long long*)ws + PUB0_U64;
  unsigned long long* const pub1 = (unsigned long long*)ws + PUB1_U64;
  unsigned* const cflg = ws + CFLG_U32 + g * 8;
  float* gb = (float*)(smem + GBUF);

#pragma unroll 1
  for (int t = 0; t < Sz + 1; ++t) {
    const bool doL0 = (t < Sz);
    const int tL = t - 1;
    const bool doL1 = (tL >= 0);

    // ---- stage layer-0 input row for step t (local; R2-verbatim) ----
    if (doL0 && tid < 160) {
      int bb = tid / 10, f4 = tid - bb * 10;
      float4 inv = *(const float4*)(xin + ((size_t)(g * 16 + bb) * Sz + t) * 40 + f4 * 4);
#pragma unroll
      for (int cc = 0; cc < 4; ++cc) {
        float f = ((const float*)&inv)[cc];
        unsigned short hb = bf16_rne(f);
        float fh = __uint_as_float((unsigned)hb << 16);
        unsigned short lb = bf16_rne(f - fh);
        int col = f4 * 4 + cc;
        *(short*)(smem + IN_HI + bb * 144 + col * 2) = (short)hb;
        *(short*)(smem + IN_LO + bb * 144 + col * 2) = (short)lb;
      }
    }

    // ---- single-RT poll: 2 sources, full reload + block vote (R2 style) ----
    // srcA0: h0(t-1), tag t  (needed by L0 recurrence AND L1 input stream)
    // srcA1: h1(t-2), tag t-1 (L1 recurrence)
    const unsigned long long* srcA0 =
        pub0 + (size_t)((g * PIPE + (t + PIPE - 1) % PIPE) * NJ) * 512;
    const unsigned long long* srcA1 =
        pub1 + (size_t)((g * PIPE + (tL - 1 + PIPE * 2) % PIPE) * NJ) * 512;
    for (;;) {
      bool ok = load_stage(srcA0, (unsigned)t, smem + HA_HI, smem + HA_LO, tid);
      if (doL1)
        ok &= load_stage(srcA1, (unsigned)tL, smem + HB_HI, smem + HB_LO, tid);
      if (tid < 8) {
        // anti-overwrite: peers must have completed staging of step t-3
        // (subsumed by srcA0's tag-wait in the main loop; binding at t=Sz tail)
        unsigned c = __hip_atomic_load(cflg + tid, __ATOMIC_RELAXED, __HIP_MEMORY_SCOPE_AGENT);
        ok &= ((int)c >= t - 2);
      }
      if (__syncthreads_and(ok)) break;
    }
    if (tid == 0)  // step-completion counter (all staging reads above are done)
      __hip_atomic_store(cflg + p, (unsigned)(t + 1), __ATOMIC_RELAXED, __HIP_MEMORY_SCOPE_AGENT);

    const int arow = n16 * 528;
    const int kcol = q * 8;

    // ================= layer 0: compute and publish FIRST =================
    if (doL0) {
      f32x4 acc0 = {0.f, 0.f, 0.f, 0.f};
      f32x4 acc1 = {0.f, 0.f, 0.f, 0.f};
#pragma unroll
      for (int kt = 0; kt < 8; ++kt) {
        short8 aH = *(const short8*)(smem + HA_HI + arow + (kt * 32 + kcol) * 2);
        short8 aL = *(const short8*)(smem + HA_LO + arow + (kt * 32 + kcol) * 2);
        acc0 = __builtin_amdgcn_mfma_f32_16x16x32_bf16(aH, wf_rec0[kt][0], acc0, 0, 0, 0);
        acc0 = __builtin_amdgcn_mfma_f32_16x16x32_bf16(aL, wf_rec0[kt][0], acc0, 0, 0, 0);
        acc1 = __builtin_amdgcn_mfma_f32_16x16x32_bf16(aH, wf_rec0[kt][1], acc1, 0, 0, 0);
        acc1 = __builtin_amdgcn_mfma_f32_16x16x32_bf16(aL, wf_rec0[kt][1], acc1, 0, 0, 0);
      }
      const int arow_in = n16 * 144;
#pragma unroll
      for (int kt = 0; kt < 2; ++kt) {
        short8 aH = *(const short8*)(smem + IN_HI + arow_in + (kt * 32 + kcol) * 2);
        short8 aL = *(const short8*)(smem + IN_LO + arow_in + (kt * 32 + kcol) * 2);
        acc0 = __builtin_amdgcn_mfma_f32_16x16x32_bf16(aH, wf_cmb[kt][0], acc0, 0, 0, 0);
        acc0 = __builtin_amdgcn_mfma_f32_16x16x32_bf16(aL, wf_cmb[kt][0], acc0, 0, 0, 0);
        acc1 = __builtin_amdgcn_mfma_f32_16x16x32_bf16(aH, wf_cmb[kt][1], acc1, 0, 0, 0);
        acc1 = __builtin_amdgcn_mfma_f32_16x16x32_bf16(aL, wf_cmb[kt][1], acc1, 0, 0, 0);
      }
#pragma unroll
      for (int u = 0; u < 2; ++u) {
        f32x4 a = u ? acc1 : acc0;
        float bs = u ? b1L0 : b0L0;
#pragma unroll
        for (int r = 0; r < 4; ++r) {
          float v = a[r] + bs;
          v = (w == 2) ? tanh_f(v) : sigm(v);
          gb[w * 528 + (q * 4 + r) * 33 + u * 16 + n16] = v;
        }
      }
      __syncthreads();
      unsigned long long* dst =
          pub0 + (size_t)((g * PIPE + (t % PIPE)) * NJ + p) * 512;
      const unsigned long long tagW = ((unsigned long long)(unsigned)(t + 1)) << 32;
#pragma unroll
      for (int k = 0; k < 2; ++k) {
        int e = tid + k * 256;
        int m = e >> 5, nn = e & 31;
        float iv = gb[0 * 528 + m * 33 + nn];
        float fv = gb[1 * 528 + m * 33 + nn];
        float gv = gb[2 * 528 + m * 33 + nn];
        float ov = gb[3 * 528 + m * 33 + nn];
        float c = k ? cL0_1 : cL0_0;
        c = fv * c + iv * gv;
        float h = ov * tanh_f(c);
        if (k) cL0_1 = c; else cL0_0 = c;
        unsigned short hb = bf16_rne(h);
        float fh = __uint_as_float((unsigned)hb << 16);
        unsigned short lb = bf16_rne(h - fh);
        unsigned pk = ((unsigned)hb << 16) | (unsigned)lb;
        __hip_atomic_store(dst + e, tagW | pk, __ATOMIC_RELAXED, __HIP_MEMORY_SCOPE_AGENT);
      }
    }

    // ============ layer 1 (step t-1): fills the old spin window ============
    if (doL1) {
      f32x4 acc0 = {0.f, 0.f, 0.f, 0.f};
      f32x4 acc1 = {0.f, 0.f, 0.f, 0.f};
#pragma unroll
      for (int kt = 0; kt < 8; ++kt) {   // recurrence: h1(t-2) @ W_hh1
        short8 aH = *(const short8*)(smem + HB_HI + arow + (kt * 32 + kcol) * 2);
        short8 aL = *(const short8*)(smem + HB_LO + arow + (kt * 32 + kcol) * 2);
        acc0 = __builtin_amdgcn_mfma_f32_16x16x32_bf16(aH, wf_rec1[kt][0], acc0, 0, 0, 0);
        acc0 = __builtin_amdgcn_mfma_f32_16x16x32_bf16(aL, wf_rec1[kt][0], acc0, 0, 0, 0);
        acc1 = __builtin_amdgcn_mfma_f32_16x16x32_bf16(aH, wf_rec1[kt][1], acc1, 0, 0, 0);
        acc1 = __builtin_amdgcn_mfma_f32_16x16x32_bf16(aL, wf_rec1[kt][1], acc1, 0, 0, 0);
      }
#pragma unroll
      for (int kt = 0; kt < 8; ++kt) {   // input stream: h0(t-1) = HA (reused!)
        short8 aH = *(const short8*)(smem + HA_HI + arow + (kt * 32 + kcol) * 2);
        short8 aL = *(const short8*)(smem + HA_LO + arow + (kt * 32 + kcol) * 2);
        acc0 = __builtin_amdgcn_mfma_f32_16x16x32_bf16(aH, wf_in2[kt][0], acc0, 0, 0, 0);
        acc0 = __builtin_amdgcn_mfma_f32_16x16x32_bf16(aL, wf_in2[kt][0], acc0, 0, 0, 0);
        acc1 = __builtin_amdgcn_mfma_f32_16x16x32_bf16(aH, wf_in2[kt][1], acc1, 0, 0, 0);
        acc1 = __builtin_amdgcn_mfma_f32_16x16x32_bf16(aL, wf_in2[kt][1], acc1, 0, 0, 0);
      }
      __syncthreads();   // all gb reads from L0 combine complete before overwrite
#pragma unroll
      for (int u = 0; u < 2; ++u) {
        f32x4 a = u ? acc1 : acc0;
        float bs = u ? b1L1 : b0L1;
#pragma unroll
        for (int r = 0; r < 4; ++r) {
          float v = a[r] + bs;
          v = (w == 2) ? tanh_f(v) : sigm(v);
          gb[w * 528 + (q * 4 + r) * 33 + u * 16 + n16] = v;
        }
      }
      __syncthreads();
      unsigned long long* dst =
          pub1 + (size_t)((g * PIPE + (tL % PIPE)) * NJ + p) * 512;
      const unsigned long long tagW = ((unsigned long long)(unsigned)(tL + 1)) << 32;
#pragma unroll
      for (int k = 0; k < 2; ++k) {
        int e = tid + k * 256;
        int m = e >> 5, nn = e & 31;
        float iv = gb[0 * 528 + m * 33 + nn];
        float fv = gb[1 * 528 + m * 33 + nn];
        float gv = gb[2 * 528 + m * 33 + nn];
        float ov = gb[3 * 528 + m * 33 + nn];
        float c = k ? cL1_1 : cL1_0;
        c = fv * c + iv * gv;
        float h = ov * tanh_f(c);
        if (k) cL1_1 = c; else cL1_0 = c;
        unsigned short hb = bf16_rne(h);
        float fh = __uint_as_float((unsigned)hb << 16);
        unsigned short lb = bf16_rne(h - fh);
        unsigned pk = ((unsigned)hb << 16) | (unsigned)lb;
        __hip_atomic_store(dst + e, tagW | pk, __ATOMIC_RELAXED, __HIP_MEMORY_SCOPE_AGENT);
        float val = h * wo;
#pragma unroll
        for (int off = 16; off; off >>= 1) val += __shfl_down(val, off, 32);
        if (nn == 0) {
          if (p == 0) val += bo;
          atomicAdd(out + (size_t)(g * 16 + m) * Sz + tL, val);
        }
      }
    }
    // no fence, no flag: tags embedded in data; next step's vote barrier
    // provides the intra-block ordering we need.
  }
}

extern "C" void kernel_launch(void* const* d_in, const int* in_sizes, int n_in,
                              void* d_out, int out_size, void* d_ws, size_t ws_size,
                              hipStream_t stream) {
  const float* xin   = (const float*)d_in[0];
  const float* W_in  = (const float*)d_in[1];
  const float* b_in  = (const float*)d_in[2];
  const float* W_ih0 = (const float*)d_in[3];
  const float* W_hh0 = (const float*)d_in[4];
  const float* b_ih0 = (const float*)d_in[5];
  const float* b_hh0 = (const float*)d_in[6];
  const float* W_ih1 = (const float*)d_in[7];
  const float* W_hh1 = (const float*)d_in[8];
  const float* b_ih1 = (const float*)d_in[9];
  const float* b_hh1 = (const float*)d_in[10];
  const float* W_out = (const float*)d_in[11];
  const float* b_out = (const float*)d_in[12];
  float* out = (float*)d_out;
  unsigned* ws = (unsigned*)d_ws;

  zero_kernel<<<(WS_U32 + 255) / 256, 256, 0, stream>>>(ws, out);
  lstm_persist<<<64, 256, 0, stream>>>(xin, W_in, b_in, W_ih0, W_hh0, b_ih0, b_hh0,
                                       W_ih1, W_hh1, b_ih1, b_hh1, W_out, b_out,
                                       out, ws);
}

// Round 7
// 9810.754 us; speedup vs baseline: 1.1855x; 1.1855x over previous
//
#include <hip/hip_runtime.h>

// 2-layer LSTM, B=64, S=2048, F=40, EMB=128, HID=256.
// Persistent design, R9: R2-exact structure + L2-fast-path polling.
//   R3-R5 (poll micro-changes) and R7/R8 (merged topology) all regressed; R6
//   re-anchored R2 at ~7650us clean. R9 keeps R2/R6 byte-identical EXCEPT the
//   poll's load cache policy: iterations alternate
//     even: sc0-only loads (bypass L1, read per-XCD L2) -- fast path. All 16
//           blocks of a group share bx&7 -> same XCD class, so producers' agent
//           write-through is visible in the shared L2 at ~200cy instead of
//           MALL ~600-900cy.
//     odd:  R2-exact agent-scope atomic loads -- durable path. Guarantees
//           forward progress under ANY block->XCD placement or cache semantics
//           (G16: correctness must not depend on XCD assignment).
//   Tags self-reject stale data: a stale L2 line carries tag <= t-4, never t.
//   Inline-asm loads use one s_waitcnt vmcnt(0) + sched_barrier(0) before use
//   (guide rule #18: compiler hoists uses past inline-asm waitcnt otherwise).
//   Numerics: weights bf16, A hi/lo bf16 split (producer-side), fp32 c/h/gates.

#define Sz    2048
#define PIPE  4
#define NG    4
#define NJ    8

typedef __attribute__((ext_vector_type(8))) short short8;
typedef __attribute__((ext_vector_type(4))) float f32x4;

// workspace layout (byte-identical to R2)
#define PUB0_U64 0            // [g][slot][p][512] u64
#define PUB1_U64 65536
#define CFLG_U32 262144       // 32 u32: layer1 consumption counters [g*8+p]
#define WS_U32   262176

// LDS byte offsets (byte-identical to R2)
#define HA_HI 0
#define HA_LO 8448
#define HB_HI 16896
#define HB_LO 25344
#define IN_HI 33792
#define IN_LO 36096
#define GBUF  38400
#define SMEM_BYTES 46848
#define WCOMB_OFF 16896   // aliases HB+IN region, used only pre-loop by layer 0

__device__ __forceinline__ unsigned short bf16_rne(float f) {
  unsigned u = __float_as_uint(f);
  u += 0x7FFFu + ((u >> 16) & 1u);
  return (unsigned short)(u >> 16);
}
__device__ __forceinline__ float sigm(float x) { return 1.f / (1.f + __expf(-x)); }
__device__ __forceinline__ float tanh_f(float x) { return 1.f - 2.f / (__expf(2.f * x) + 1.f); }

// R2-verbatim durable path: agent-scope atomic loads (L1+L2 bypass, MALL RT).
__device__ __forceinline__ bool load_stage(const unsigned long long* __restrict__ src,
                                           unsigned tagExp, char* hi, char* lo, int tid) {
  unsigned long long v[16];
#pragma unroll
  for (int kt = 0; kt < 8; ++kt) {
    v[kt * 2]     = __hip_atomic_load(src + kt * 512 + tid,       __ATOMIC_RELAXED, __HIP_MEMORY_SCOPE_AGENT);
    v[kt * 2 + 1] = __hip_atomic_load(src + kt * 512 + 256 + tid, __ATOMIC_RELAXED, __HIP_MEMORY_SCOPE_AGENT);
  }
  bool ok = true;
#pragma unroll
  for (int kt = 0; kt < 8; ++kt) {
#pragma unroll
    for (int hh = 0; hh < 2; ++hh) {
      unsigned long long x = v[kt * 2 + hh];
      ok &= ((unsigned)(x >> 32) == tagExp);
      unsigned pk = (unsigned)x;
      int e = tid + hh * 256;
      int m = e >> 5, col = kt * 32 + (e & 31);
      *(short*)(hi + m * 528 + col * 2) = (short)(pk >> 16);
      *(short*)(lo + m * 528 + col * 2) = (short)(pk & 0xffffu);
    }
  }
  return ok;
}

// Fast path: sc0-only loads (bypass L1, served by per-XCD L2 when the producer
// is XCD-local). Issue all 16, single waitcnt, sched_barrier fence (rule #18).
__device__ __forceinline__ bool load_stage_fast(const unsigned long long* __restrict__ src,
                                                unsigned tagExp, char* hi, char* lo, int tid) {
  unsigned long long v[16];
#pragma unroll
  for (int kt = 0; kt < 8; ++kt) {
    asm volatile("global_load_dwordx2 %0, %1, off sc0"
                 : "=v"(v[kt * 2]) : "v"(src + kt * 512 + tid));
    asm volatile("global_load_dwordx2 %0, %1, off sc0"
                 : "=v"(v[kt * 2 + 1]) : "v"(src + kt * 512 + 256 + tid));
  }
  asm volatile("s_waitcnt vmcnt(0)" ::: "memory");
  __builtin_amdgcn_sched_barrier(0);
  bool ok = true;
#pragma unroll
  for (int kt = 0; kt < 8; ++kt) {
#pragma unroll
    for (int hh = 0; hh < 2; ++hh) {
      unsigned long long x = v[kt * 2 + hh];
      ok &= ((unsigned)(x >> 32) == tagExp);
      unsigned pk = (unsigned)x;
      int e = tid + hh * 256;
      int m = e >> 5, col = kt * 32 + (e & 31);
      *(short*)(hi + m * 528 + col * 2) = (short)(pk >> 16);
      *(short*)(lo + m * 528 + col * 2) = (short)(pk & 0xffffu);
    }
  }
  return ok;
}

__device__ __forceinline__ unsigned ld32_sc0(const unsigned* p) {
  unsigned v;
  asm volatile("global_load_dword %0, %1, off sc0\n\ts_waitcnt vmcnt(0)"
               : "=v"(v) : "v"(p) : "memory");
  return v;
}

__global__ void zero_kernel(unsigned* __restrict__ ws, float* __restrict__ out) {
  int i = blockIdx.x * 256 + threadIdx.x;
  if (i < WS_U32) ws[i] = 0u;
  if (i < 64 * Sz) out[i] = 0.f;
}

__global__ __launch_bounds__(256, 1) void lstm_persist(
    const float* __restrict__ xin, const float* __restrict__ W_in,
    const float* __restrict__ b_in, const float* __restrict__ W_ih0,
    const float* __restrict__ W_hh0, const float* __restrict__ b_ih0,
    const float* __restrict__ b_hh0, const float* __restrict__ W_ih1,
    const float* __restrict__ W_hh1, const float* __restrict__ b_ih1,
    const float* __restrict__ b_hh1, const float* __restrict__ W_out,
    const float* __restrict__ b_out, float* __restrict__ out,
    unsigned* __restrict__ ws) {
  const int bx = blockIdx.x;
  const int g = bx & 7;          // group -> XCD class (locality heuristic only)
  if (g >= NG) return;
  const int idx = bx >> 3;       // 0..15
  const int layer = idx >> 3;    // 0 or 1
  const int p = idx & 7;         // j-split slice
  const int tid = (int)threadIdx.x;
  const int w = tid >> 6;        // wave = gate (i,f,g,o)
  const int lane = tid & 63;
  const int q = lane >> 4;
  const int n16 = lane & 15;

  __shared__ __align__(16) char smem[SMEM_BYTES];

  const int row0 = w * 256 + p * 32 + n16;   // absolute gate rows (u=0,1)
  const int row1 = row0 + 16;

  short8 wf_rec[8][2];   // W_hh frags [ktile][u]
  short8 wf_in2[8][2];   // layer1: W_ih1 frags
  short8 wf_cmb[2][2];   // layer0: W_comb frags (K padded 40->64)
  float bias0 = 0.f, bias1 = 0.f;

  // ---------------- startup: persistent weight fragments ----------------
  {
    const float* Wrec = layer ? W_hh1 : W_hh0;
#pragma unroll
    for (int kt = 0; kt < 8; ++kt) {
#pragma unroll
      for (int u = 0; u < 2; ++u) {
        const int row = u ? row1 : row0;
        const float* src = Wrec + (size_t)row * 256 + kt * 32 + q * 8;
        union { short8 v; unsigned short s[8]; } fr;
#pragma unroll
        for (int j = 0; j < 8; ++j) fr.s[j] = bf16_rne(src[j]);
        wf_rec[kt][u] = fr.v;
      }
    }
  }
  if (layer == 1) {
#pragma unroll
    for (int kt = 0; kt < 8; ++kt) {
#pragma unroll
      for (int u = 0; u < 2; ++u) {
        const int row = u ? row1 : row0;
        const float* src = W_ih1 + (size_t)row * 256 + kt * 32 + q * 8;
        union { short8 v; unsigned short s[8]; } fr;
#pragma unroll
        for (int j = 0; j < 8; ++j) fr.s[j] = bf16_rne(src[j]);
        wf_in2[kt][u] = fr.v;
      }
    }
    bias0 = b_ih1[row0] + b_hh1[row0];
    bias1 = b_ih1[row1] + b_hh1[row1];
  } else {
    // W_comb = W_ih0 @ W_in for this block's 128 gate rows, staged via LDS
    float* wcomb = (float*)(smem + WCOMB_OFF);
    for (int i = tid; i < 128 * 40; i += 256) {
      int rl = i / 40, f = i - rl * 40;
      int gate = rl >> 5, rr = rl & 31;
      int arow = gate * 256 + p * 32 + rr;
      const float* wi = W_ih0 + (size_t)arow * 128;
      float s = 0.f;
      for (int e = 0; e < 128; ++e) s += wi[e] * W_in[e * 40 + f];
      wcomb[rl * 40 + f] = s;
    }
    __syncthreads();
#pragma unroll
    for (int kt = 0; kt < 2; ++kt) {
#pragma unroll
      for (int u = 0; u < 2; ++u) {
        int rl = w * 32 + u * 16 + n16;
        union { short8 v; unsigned short s[8]; } fr;
#pragma unroll
        for (int j = 0; j < 8; ++j) {
          int k = kt * 32 + q * 8 + j;
          fr.s[j] = (k < 40) ? bf16_rne(wcomb[rl * 40 + k]) : (unsigned short)0;
        }
        wf_cmb[kt][u] = fr.v;
      }
    }
    {
      const float* wi0 = W_ih0 + (size_t)row0 * 128;
      const float* wi1 = W_ih0 + (size_t)row1 * 128;
      float s0 = 0.f, s1 = 0.f;
      for (int e = 0; e < 128; ++e) { s0 += wi0[e] * b_in[e]; s1 += wi1[e] * b_in[e]; }
      bias0 = s0 + b_ih0[row0] + b_hh0[row0];
      bias1 = s1 + b_ih0[row1] + b_hh0[row1];
    }
    __syncthreads();  // done with wcomb alias
    // zero input planes once (cols 40..63 stay zero forever)
    for (int i = tid; i < 2304; i += 256) *((short*)(smem + IN_HI) + i) = 0;
    __syncthreads();
  }

  float c0 = 0.f, c1 = 0.f;   // cell state, elements e=tid and e=tid+256
  float wo = 0.f, bo = 0.f;
  if (layer == 1) { wo = W_out[p * 32 + (tid & 31)]; bo = b_out[0]; }

  unsigned long long* const pub0 = (unsigned long long*)ws + PUB0_U64;
  unsigned long long* const pub1 = (unsigned long long*)ws + PUB1_U64;
  unsigned long long* const pubMy = layer ? pub1 : pub0;
  unsigned* const cflg = ws + CFLG_U32 + g * 8;
  float* gb = (float*)(smem + GBUF);

#pragma unroll 1
  for (int t = 0; t < Sz; ++t) {
    // ---- stage layer-0 input row for step t (local, no sync needed yet) ----
    if (layer == 0 && tid < 160) {
      int bb = tid / 10, f4 = tid - bb * 10;
      float4 inv = *(const float4*)(xin + ((size_t)(g * 16 + bb) * Sz + t) * 40 + f4 * 4);
#pragma unroll
      for (int cc = 0; cc < 4; ++cc) {
        float f = ((const float*)&inv)[cc];
        unsigned short hb = bf16_rne(f);
        float fh = __uint_as_float((unsigned)hb << 16);
        unsigned short lb = bf16_rne(f - fh);
        int col = f4 * 4 + cc;
        *(short*)(smem + IN_HI + bb * 144 + col * 2) = (short)hb;
        *(short*)(smem + IN_LO + bb * 144 + col * 2) = (short)lb;
      }
    }

    // ---- poll: R2 structure; even iterations L2-fast, odd iterations durable ----
    const int slot_r = (t + PIPE - 1) % PIPE;                 // h(t-1) of own layer
    const unsigned long long* srcA = pubMy + (size_t)((g * PIPE + slot_r) * NJ) * 512;
    const unsigned long long* srcB = pub0 + (size_t)((g * PIPE + (t % PIPE)) * NJ) * 512; // h0(t)
    const unsigned tagA = (unsigned)t;        // h(t-1) carries tag t
    const unsigned tagB = (unsigned)(t + 1);  // h0(t) carries tag t+1
    for (int it = 0;; ++it) {
      const bool fastp = ((it & 1) == 0);
      bool ok = fastp ? load_stage_fast(srcA, tagA, smem + HA_HI, smem + HA_LO, tid)
                      : load_stage(srcA, tagA, smem + HA_HI, smem + HA_LO, tid);
      if (layer == 1) {
        ok &= fastp ? load_stage_fast(srcB, tagB, smem + HB_HI, smem + HB_LO, tid)
                    : load_stage(srcB, tagB, smem + HB_HI, smem + HB_LO, tid);
      } else if (tid < 8) {
        // anti-overwrite: layer1 must have consumed step (t-4) inputs
        unsigned c = fastp ? ld32_sc0(cflg + tid)
                           : __hip_atomic_load(cflg + tid, __ATOMIC_RELAXED, __HIP_MEMORY_SCOPE_AGENT);
        ok &= ((int)c >= t - 3);
      }
      if (__syncthreads_and(ok)) break;
    }
    if (layer == 1 && tid == 0)  // consumption counter (reads above are complete)
      __hip_atomic_store(cflg + p, (unsigned)(t + 1), __ATOMIC_RELAXED, __HIP_MEMORY_SCOPE_AGENT);

    // ---- MFMA: gates = hprev@Whh^T (+ input stream) ----
    f32x4 acc0 = {0.f, 0.f, 0.f, 0.f};
    f32x4 acc1 = {0.f, 0.f, 0.f, 0.f};
    const int arow = n16 * 528;
    const int kcol = q * 8;
#pragma unroll
    for (int kt = 0; kt < 8; ++kt) {
      short8 aH = *(const short8*)(smem + HA_HI + arow + (kt * 32 + kcol) * 2);
      short8 aL = *(const short8*)(smem + HA_LO + arow + (kt * 32 + kcol) * 2);
      acc0 = __builtin_amdgcn_mfma_f32_16x16x32_bf16(aH, wf_rec[kt][0], acc0, 0, 0, 0);
      acc0 = __builtin_amdgcn_mfma_f32_16x16x32_bf16(aL, wf_rec[kt][0], acc0, 0, 0, 0);
      acc1 = __builtin_amdgcn_mfma_f32_16x16x32_bf16(aH, wf_rec[kt][1], acc1, 0, 0, 0);
      acc1 = __builtin_amdgcn_mfma_f32_16x16x32_bf16(aL, wf_rec[kt][1], acc1, 0, 0, 0);
    }
    if (layer == 1) {
#pragma unroll
      for (int kt = 0; kt < 8; ++kt) {
        short8 aH = *(const short8*)(smem + HB_HI + arow + (kt * 32 + kcol) * 2);
        short8 aL = *(const short8*)(smem + HB_LO + arow + (kt * 32 + kcol) * 2);
        acc0 = __builtin_amdgcn_mfma_f32_16x16x32_bf16(aH, wf_in2[kt][0], acc0, 0, 0, 0);
        acc0 = __builtin_amdgcn_mfma_f32_16x16x32_bf16(aL, wf_in2[kt][0], acc0, 0, 0, 0);
        acc1 = __builtin_amdgcn_mfma_f32_16x16x32_bf16(aH, wf_in2[kt][1], acc1, 0, 0, 0);
        acc1 = __builtin_amdgcn_mfma_f32_16x16x32_bf16(aL, wf_in2[kt][1], acc1, 0, 0, 0);
      }
    } else {
      const int arow_in = n16 * 144;
#pragma unroll
      for (int kt = 0; kt < 2; ++kt) {
        short8 aH = *(const short8*)(smem + IN_HI + arow_in + (kt * 32 + kcol) * 2);
        short8 aL = *(const short8*)(smem + IN_LO + arow_in + (kt * 32 + kcol) * 2);
        acc0 = __builtin_amdgcn_mfma_f32_16x16x32_bf16(aH, wf_cmb[kt][0], acc0, 0, 0, 0);
        acc0 = __builtin_amdgcn_mfma_f32_16x16x32_bf16(aL, wf_cmb[kt][0], acc0, 0, 0, 0);
        acc1 = __builtin_amdgcn_mfma_f32_16x16x32_bf16(aH, wf_cmb[kt][1], acc1, 0, 0, 0);
        acc1 = __builtin_amdgcn_mfma_f32_16x16x32_bf16(aL, wf_cmb[kt][1], acc1, 0, 0, 0);
      }
    }

    // ---- epilogue: activation per gate-wave, share via LDS ----
#pragma unroll
    for (int u = 0; u < 2; ++u) {
      f32x4 a = u ? acc1 : acc0;
      float bs = u ? bias1 : bias0;
#pragma unroll
      for (int r = 0; r < 4; ++r) {
        float v = a[r] + bs;
        v = (w == 2) ? tanh_f(v) : sigm(v);
        gb[w * 528 + (q * 4 + r) * 33 + u * 16 + n16] = v;
      }
    }
    __syncthreads();

    // ---- combine gates, update c/h, publish {tag, bf16hi|bf16lo} ----
    unsigned long long* dst =
        pubMy + (size_t)((g * PIPE + (t % PIPE)) * NJ + p) * 512;
    const unsigned long long tagW = ((unsigned long long)(unsigned)(t + 1)) << 32;
#pragma unroll
    for (int k = 0; k < 2; ++k) {
      int e = tid + k * 256;
      int m = e >> 5, nn = e & 31;
      float iv = gb[0 * 528 + m * 33 + nn];
      float fv = gb[1 * 528 + m * 33 + nn];
      float gv = gb[2 * 528 + m * 33 + nn];
      float ov = gb[3 * 528 + m * 33 + nn];
      float c = k ? c1 : c0;
      c = fv * c + iv * gv;
      float h = ov * tanh_f(c);
      if (k) c1 = c; else c0 = c;
      unsigned short hb = bf16_rne(h);
      float fh = __uint_as_float((unsigned)hb << 16);
      unsigned short lb = bf16_rne(h - fh);
      unsigned pk = ((unsigned)hb << 16) | (unsigned)lb;
      __hip_atomic_store(dst + e, tagW | pk, __ATOMIC_RELAXED, __HIP_MEMORY_SCOPE_AGENT);
      if (layer == 1) {
        float val = h * wo;
#pragma unroll
        for (int off = 16; off; off >>= 1) val += __shfl_down(val, off, 32);
        if (nn == 0) {
          if (p == 0) val += bo;
          atomicAdd(out + (size_t)(g * 16 + m) * Sz + t, val);
        }
      }
    }
    // no fence, no flag: tags embedded in data; next step's vote barrier
    // provides the intra-block ordering we need.
  }
}

extern "C" void kernel_launch(void* const* d_in, const int* in_sizes, int n_in,
                              void* d_out, int out_size, void* d_ws, size_t ws_size,
                              hipStream_t stream) {
  const float* xin   = (const float*)d_in[0];
  const float* W_in  = (const float*)d_in[1];
  const float* b_in  = (const float*)d_in[2];
  const float* W_ih0 = (const float*)d_in[3];
  const float* W_hh0 = (const float*)d_in[4];
  const float* b_ih0 = (const float*)d_in[5];
  const float* b_hh0 = (const float*)d_in[6];
  const float* W_ih1 = (const float*)d_in[7];
  const float* W_hh1 = (const float*)d_in[8];
  const float* b_ih1 = (const float*)d_in[9];
  const float* b_hh1 = (const float*)d_in[10];
  const float* W_out = (const float*)d_in[11];
  const float* b_out = (const float*)d_in[12];
  float* out = (float*)d_out;
  unsigned* ws = (unsigned*)d_ws;

  zero_kernel<<<(WS_U32 + 255) / 256, 256, 0, stream>>>(ws, out);
  lstm_persist<<<128, 256, 0, stream>>>(xin, W_in, b_in, W_ih0, W_hh0, b_ih0, b_hh0,
                                        W_ih1, W_hh1, b_ih1, b_hh1, W_out, b_out,
                                        out, ws);
}

// Round 8
// 9085.962 us; speedup vs baseline: 1.2801x; 1.0798x over previous
//
#include <hip/hip_runtime.h>

// 2-layer LSTM, B=64, S=2048, F=40, EMB=128, HID=256.
// Persistent design, R10: COARSENED cohort — NJ=4 slices x 512-thread blocks.
//   R2/R6 protocol verbatim (full tagged reload every poll iteration, block
//   vote, cflg guard, PIPE=4 ring, same workspace bytes). Change: each block
//   owns 64 h-cols (=256 gate rows) with 8 waves instead of 32 cols/4 waves.
//   -> 4 producers per layer-group (fan-in 4), 8 voters per cohort (was 16),
//   poll traffic per step halved, per-wave MFMA work UNCHANGED (no compute
//   added to the recurrence critical path — the R8 mistake is not repeated).
//   32 active blocks (64 launched, g=bx&7<4 keeps XCD-class grouping).
//   Numerics identical: weights bf16, A hi/lo bf16 split, fp32 c/h/gates.

#define Sz    2048
#define PIPE  4
#define NG    4
#define NJ    4

typedef __attribute__((ext_vector_type(8))) short short8;
typedef __attribute__((ext_vector_type(4))) float f32x4;

// workspace layout (byte-identical to R2: slot = 4096 u64 per group)
#define PUB0_U64 0            // [g][slot(4)][slab(4)][1024] u64
#define PUB1_U64 65536
#define CFLG_U32 262144       // consumption counters [g*8+p] (p<4 used)
#define WS_U32   262176

// LDS byte offsets
#define HA_HI 0               // own-layer h(t-1): 16 rows x 528B
#define HA_LO 8448
#define HB_HI 16896           // layer1: h0(t)
#define HB_LO 25344
#define IN_HI 33792           // layer0: xin(t) bf16 planes (pad 40->64)
#define IN_LO 36096
#define GBUF  38400           // 4 gates x 16 x 65 floats = 16640B
#define SMEM_BYTES 55040
#define WCOMB_OFF 0           // aliases HA/HB region, used only pre-loop (L0)

__device__ __forceinline__ unsigned short bf16_rne(float f) {
  unsigned u = __float_as_uint(f);
  u += 0x7FFFu + ((u >> 16) & 1u);
  return (unsigned short)(u >> 16);
}
__device__ __forceinline__ float sigm(float x) { return 1.f / (1.f + __expf(-x)); }
__device__ __forceinline__ float tanh_f(float x) { return 1.f - 2.f / (__expf(2.f * x) + 1.f); }

// Load one slot (4 slabs x 1024 u64) across 512 threads, check embedded tags,
// stage bf16 hi/lo planes into LDS. Returns per-thread tag-ok predicate.
__device__ __forceinline__ bool load_stage(const unsigned long long* __restrict__ src,
                                           unsigned tagExp, char* hi, char* lo, int tid) {
  unsigned long long v[8];
#pragma unroll
  for (int kt = 0; kt < 4; ++kt) {
    v[kt * 2]     = __hip_atomic_load(src + kt * 1024 + tid,       __ATOMIC_RELAXED, __HIP_MEMORY_SCOPE_AGENT);
    v[kt * 2 + 1] = __hip_atomic_load(src + kt * 1024 + 512 + tid, __ATOMIC_RELAXED, __HIP_MEMORY_SCOPE_AGENT);
  }
  bool ok = true;
#pragma unroll
  for (int kt = 0; kt < 4; ++kt) {
#pragma unroll
    for (int hh = 0; hh < 2; ++hh) {
      unsigned long long x = v[kt * 2 + hh];
      ok &= ((unsigned)(x >> 32) == tagExp);
      unsigned pk = (unsigned)x;
      int e = tid + hh * 512;
      int m = e >> 6, col = kt * 64 + (e & 63);
      *(short*)(hi + m * 528 + col * 2) = (short)(pk >> 16);
      *(short*)(lo + m * 528 + col * 2) = (short)(pk & 0xffffu);
    }
  }
  return ok;
}

__global__ void zero_kernel(unsigned* __restrict__ ws, float* __restrict__ out) {
  int i = blockIdx.x * 256 + threadIdx.x;
  if (i < WS_U32) ws[i] = 0u;
  if (i < 64 * Sz) out[i] = 0.f;
}

__global__ __launch_bounds__(512, 1) void lstm_persist(
    const float* __restrict__ xin, const float* __restrict__ W_in,
    const float* __restrict__ b_in, const float* __restrict__ W_ih0,
    const float* __restrict__ W_hh0, const float* __restrict__ b_ih0,
    const float* __restrict__ b_hh0, const float* __restrict__ W_ih1,
    const float* __restrict__ W_hh1, const float* __restrict__ b_ih1,
    const float* __restrict__ b_hh1, const float* __restrict__ W_out,
    const float* __restrict__ b_out, float* __restrict__ out,
    unsigned* __restrict__ ws) {
  const int bx = blockIdx.x;
  const int g = bx & 7;          // group -> XCD class (locality heuristic only)
  if (g >= NG) return;
  const int idx = bx >> 3;       // 0..7
  const int layer = idx >> 2;    // 0 or 1
  const int p = idx & 3;         // j-split slice (64 cols)
  const int tid = (int)threadIdx.x;
  const int w = tid >> 6;        // wave 0..7: gate = w>>1, col-half = w&1
  const int g2 = w >> 1;         // gate (i,f,g,o)
  const int ch = w & 1;          // 32-col half within the block's 64-col slice
  const int lane = tid & 63;
  const int q = lane >> 4;
  const int n16 = lane & 15;

  __shared__ __align__(16) char smem[SMEM_BYTES];

  const int row0 = g2 * 256 + p * 64 + ch * 32 + n16;  // absolute gate rows
  const int row1 = row0 + 16;

  short8 wf_rec[8][2];   // W_hh frags [ktile][u]
  short8 wf_in2[8][2];   // layer1: W_ih1 frags
  short8 wf_cmb[2][2];   // layer0: W_comb frags (K padded 40->64)
  float bias0 = 0.f, bias1 = 0.f;

  // ---------------- startup: persistent weight fragments ----------------
  {
    const float* Wrec = layer ? W_hh1 : W_hh0;
#pragma unroll
    for (int kt = 0; kt < 8; ++kt) {
#pragma unroll
      for (int u = 0; u < 2; ++u) {
        const int row = u ? row1 : row0;
        const float* src = Wrec + (size_t)row * 256 + kt * 32 + q * 8;
        union { short8 v; unsigned short s[8]; } fr;
#pragma unroll
        for (int j = 0; j < 8; ++j) fr.s[j] = bf16_rne(src[j]);
        wf_rec[kt][u] = fr.v;
      }
    }
  }
  if (layer == 1) {
#pragma unroll
    for (int kt = 0; kt < 8; ++kt) {
#pragma unroll
      for (int u = 0; u < 2; ++u) {
        const int row = u ? row1 : row0;
        const float* src = W_ih1 + (size_t)row * 256 + kt * 32 + q * 8;
        union { short8 v; unsigned short s[8]; } fr;
#pragma unroll
        for (int j = 0; j < 8; ++j) fr.s[j] = bf16_rne(src[j]);
        wf_in2[kt][u] = fr.v;
      }
    }
    bias0 = b_ih1[row0] + b_hh1[row0];
    bias1 = b_ih1[row1] + b_hh1[row1];
  } else {
    // W_comb = W_ih0 @ W_in for this block's 256 gate rows, staged via LDS
    float* wcomb = (float*)(smem + WCOMB_OFF);   // 256*40*4 = 40960B
    for (int i = tid; i < 256 * 40; i += 512) {
      int rl = i / 40, f = i - rl * 40;
      int gate = rl >> 6, rr = rl & 63;
      int arow = gate * 256 + p * 64 + rr;
      const float* wi = W_ih0 + (size_t)arow * 128;
      float s = 0.f;
      for (int e = 0; e < 128; ++e) s += wi[e] * W_in[e * 40 + f];
      wcomb[rl * 40 + f] = s;
    }
    __syncthreads();
#pragma unroll
    for (int kt = 0; kt < 2; ++kt) {
#pragma unroll
      for (int u = 0; u < 2; ++u) {
        int rl = g2 * 64 + ch * 32 + u * 16 + n16;   // within-block row 0..255
        union { short8 v; unsigned short s[8]; } fr;
#pragma unroll
        for (int j = 0; j < 8; ++j) {
          int k = kt * 32 + q * 8 + j;
          fr.s[j] = (k < 40) ? bf16_rne(wcomb[rl * 40 + k]) : (unsigned short)0;
        }
        wf_cmb[kt][u] = fr.v;
      }
    }
    {
      const float* wi0 = W_ih0 + (size_t)row0 * 128;
      const float* wi1 = W_ih0 + (size_t)row1 * 128;
      float s0 = 0.f, s1 = 0.f;
      for (int e = 0; e < 128; ++e) { s0 += wi0[e] * b_in[e]; s1 += wi1[e] * b_in[e]; }
      bias0 = s0 + b_ih0[row0] + b_hh0[row0];
      bias1 = s1 + b_ih0[row1] + b_hh0[row1];
    }
    __syncthreads();  // done with wcomb alias (HA/HB region)
    // zero input planes once (cols 40..63 stay zero forever; HI+LO = 4608B)
    for (int i = tid; i < 2304; i += 512) *((short*)(smem + IN_HI) + i) = 0;
    __syncthreads();
  }

  float c0 = 0.f, c1 = 0.f;   // cell state, elements e=tid and e=tid+512
  float wo = 0.f, bo = 0.f;
  if (layer == 1) { wo = W_out[p * 64 + lane]; bo = b_out[0]; }

  unsigned long long* const pub0 = (unsigned long long*)ws + PUB0_U64;
  unsigned long long* const pub1 = (unsigned long long*)ws + PUB1_U64;
  unsigned long long* const pubMy = layer ? pub1 : pub0;
  unsigned* const cflg = ws + CFLG_U32 + g * 8;
  float* gb = (float*)(smem + GBUF);   // [gate][m][col] strides 1040/65/1

#pragma unroll 1
  for (int t = 0; t < Sz; ++t) {
    // ---- stage layer-0 input row for step t (local, no sync needed yet) ----
    if (layer == 0 && tid < 160) {
      int bb = tid / 10, f4 = tid - bb * 10;
      float4 inv = *(const float4*)(xin + ((size_t)(g * 16 + bb) * Sz + t) * 40 + f4 * 4);
#pragma unroll
      for (int cc = 0; cc < 4; ++cc) {
        float f = ((const float*)&inv)[cc];
        unsigned short hb = bf16_rne(f);
        float fh = __uint_as_float((unsigned)hb << 16);
        unsigned short lb = bf16_rne(f - fh);
        int col = f4 * 4 + cc;
        *(short*)(smem + IN_HI + bb * 144 + col * 2) = (short)hb;
        *(short*)(smem + IN_LO + bb * 144 + col * 2) = (short)lb;
      }
    }

    // ---- single-RT poll: full reload + block vote (R2-exact discipline) ----
    const int slot_r = (t + PIPE - 1) % PIPE;                 // h(t-1) of own layer
    const unsigned long long* srcA = pubMy + (size_t)((g * PIPE + slot_r) * NJ) * 1024;
    const unsigned long long* srcB = pub0 + (size_t)((g * PIPE + (t % PIPE)) * NJ) * 1024; // h0(t)
    const unsigned tagA = (unsigned)t;        // h(t-1) carries tag t
    const unsigned tagB = (unsigned)(t + 1);  // h0(t) carries tag t+1
    for (;;) {
      bool ok = load_stage(srcA, tagA, smem + HA_HI, smem + HA_LO, tid);
      if (layer == 1) {
        ok &= load_stage(srcB, tagB, smem + HB_HI, smem + HB_LO, tid);
      } else if (tid < NJ) {
        // anti-overwrite: layer1 must have consumed step (t-4) inputs
        unsigned c = __hip_atomic_load(cflg + tid, __ATOMIC_RELAXED, __HIP_MEMORY_SCOPE_AGENT);
        ok &= ((int)c >= t - 3);
      }
      if (__syncthreads_and(ok)) break;
    }
    if (layer == 1 && tid == 0)  // consumption counter (reads above are complete)
      __hip_atomic_store(cflg + p, (unsigned)(t + 1), __ATOMIC_RELAXED, __HIP_MEMORY_SCOPE_AGENT);

    // ---- MFMA: gates = hprev@Whh^T (+ input stream); per-wave work == R2 ----
    f32x4 acc0 = {0.f, 0.f, 0.f, 0.f};
    f32x4 acc1 = {0.f, 0.f, 0.f, 0.f};
    const int arow = n16 * 528;
    const int kcol = q * 8;
#pragma unroll
    for (int kt = 0; kt < 8; ++kt) {
      short8 aH = *(const short8*)(smem + HA_HI + arow + (kt * 32 + kcol) * 2);
      short8 aL = *(const short8*)(smem + HA_LO + arow + (kt * 32 + kcol) * 2);
      acc0 = __builtin_amdgcn_mfma_f32_16x16x32_bf16(aH, wf_rec[kt][0], acc0, 0, 0, 0);
      acc0 = __builtin_amdgcn_mfma_f32_16x16x32_bf16(aL, wf_rec[kt][0], acc0, 0, 0, 0);
      acc1 = __builtin_amdgcn_mfma_f32_16x16x32_bf16(aH, wf_rec[kt][1], acc1, 0, 0, 0);
      acc1 = __builtin_amdgcn_mfma_f32_16x16x32_bf16(aL, wf_rec[kt][1], acc1, 0, 0, 0);
    }
    if (layer == 1) {
#pragma unroll
      for (int kt = 0; kt < 8; ++kt) {
        short8 aH = *(const short8*)(smem + HB_HI + arow + (kt * 32 + kcol) * 2);
        short8 aL = *(const short8*)(smem + HB_LO + arow + (kt * 32 + kcol) * 2);
        acc0 = __builtin_amdgcn_mfma_f32_16x16x32_bf16(aH, wf_in2[kt][0], acc0, 0, 0, 0);
        acc0 = __builtin_amdgcn_mfma_f32_16x16x32_bf16(aL, wf_in2[kt][0], acc0, 0, 0, 0);
        acc1 = __builtin_amdgcn_mfma_f32_16x16x32_bf16(aH, wf_in2[kt][1], acc1, 0, 0, 0);
        acc1 = __builtin_amdgcn_mfma_f32_16x16x32_bf16(aL, wf_in2[kt][1], acc1, 0, 0, 0);
      }
    } else {
      const int arow_in = n16 * 144;
#pragma unroll
      for (int kt = 0; kt < 2; ++kt) {
        short8 aH = *(const short8*)(smem + IN_HI + arow_in + (kt * 32 + kcol) * 2);
        short8 aL = *(const short8*)(smem + IN_LO + arow_in + (kt * 32 + kcol) * 2);
        acc0 = __builtin_amdgcn_mfma_f32_16x16x32_bf16(aH, wf_cmb[kt][0], acc0, 0, 0, 0);
        acc0 = __builtin_amdgcn_mfma_f32_16x16x32_bf16(aL, wf_cmb[kt][0], acc0, 0, 0, 0);
        acc1 = __builtin_amdgcn_mfma_f32_16x16x32_bf16(aH, wf_cmb[kt][1], acc1, 0, 0, 0);
        acc1 = __builtin_amdgcn_mfma_f32_16x16x32_bf16(aL, wf_cmb[kt][1], acc1, 0, 0, 0);
      }
    }

    // ---- epilogue: activation per gate-wave, share via LDS ----
#pragma unroll
    for (int u = 0; u < 2; ++u) {
      f32x4 a = u ? acc1 : acc0;
      float bs = u ? bias1 : bias0;
#pragma unroll
      for (int r = 0; r < 4; ++r) {
        float v = a[r] + bs;
        v = (g2 == 2) ? tanh_f(v) : sigm(v);
        gb[g2 * 1040 + (q * 4 + r) * 65 + ch * 32 + u * 16 + n16] = v;
      }
    }
    __syncthreads();

    // ---- combine gates, update c/h, publish {tag, bf16hi|bf16lo} ----
    unsigned long long* dst =
        pubMy + (size_t)((g * PIPE + (t % PIPE)) * NJ + p) * 1024;
    const unsigned long long tagW = ((unsigned long long)(unsigned)(t + 1)) << 32;
#pragma unroll
    for (int k = 0; k < 2; ++k) {
      int e = tid + k * 512;
      int m = e >> 6, nn = e & 63;
      float iv = gb[0 * 1040 + m * 65 + nn];
      float fv = gb[1 * 1040 + m * 65 + nn];
      float gv = gb[2 * 1040 + m * 65 + nn];
      float ov = gb[3 * 1040 + m * 65 + nn];
      float c = k ? c1 : c0;
      c = fv * c + iv * gv;
      float h = ov * tanh_f(c);
      if (k) c1 = c; else c0 = c;
      unsigned short hb = bf16_rne(h);
      float fh = __uint_as_float((unsigned)hb << 16);
      unsigned short lb = bf16_rne(h - fh);
      unsigned pk = ((unsigned)hb << 16) | (unsigned)lb;
      __hip_atomic_store(dst + e, tagW | pk, __ATOMIC_RELAXED, __HIP_MEMORY_SCOPE_AGENT);
      if (layer == 1) {
        float val = h * wo;   // 64 cols of batch m live in one wave
#pragma unroll
        for (int off = 32; off; off >>= 1) val += __shfl_down(val, off, 64);
        if (nn == 0) {
          if (p == 0) val += bo;
          atomicAdd(out + (size_t)(g * 16 + m) * Sz + t, val);
        }
      }
    }
    // no fence, no flag: tags embedded in data; next step's vote barrier
    // provides the intra-block ordering we need.
  }
}

extern "C" void kernel_launch(void* const* d_in, const int* in_sizes, int n_in,
                              void* d_out, int out_size, void* d_ws, size_t ws_size,
                              hipStream_t stream) {
  const float* xin   = (const float*)d_in[0];
  const float* W_in  = (const float*)d_in[1];
  const float* b_in  = (const float*)d_in[2];
  const float* W_ih0 = (const float*)d_in[3];
  const float* W_hh0 = (const float*)d_in[4];
  const float* b_ih0 = (const float*)d_in[5];
  const float* b_hh0 = (const float*)d_in[6];
  const float* W_ih1 = (const float*)d_in[7];
  const float* W_hh1 = (const float*)d_in[8];
  const float* b_ih1 = (const float*)d_in[9];
  const float* b_hh1 = (const float*)d_in[10];
  const float* W_out = (const float*)d_in[11];
  const float* b_out = (const float*)d_in[12];
  float* out = (float*)d_out;
  unsigned* ws = (unsigned*)d_ws;

  zero_kernel<<<(WS_U32 + 255) / 256, 256, 0, stream>>>(ws, out);
  lstm_persist<<<64, 512, 0, stream>>>(xin, W_in, b_in, W_ih0, W_hh0, b_ih0, b_hh0,
                                       W_ih1, W_hh1, b_ih1, b_hh1, W_out, b_out,
                                       out, ws);
}